// Round 3
// baseline (1155.006 us; speedup 1.0000x reference)
//
#include <hip/hip_runtime.h>
#include <stdint.h>

using u16 = unsigned short;
typedef __attribute__((ext_vector_type(8))) short short8;   // 8 bf16 (4 VGPRs) MFMA A/B frag
typedef __attribute__((ext_vector_type(4))) float floatx4;  // MFMA C/D frag

__device__ __forceinline__ float b2f(u16 s) {
    union { unsigned u; float f; } x; x.u = ((unsigned)s) << 16; return x.f;
}
__device__ __forceinline__ u16 f2b(float f) {
    unsigned u = __float_as_uint(f);
    unsigned r = (u + 0x7fffu + ((u >> 16) & 1u)) >> 16;  // RNE
    return (u16)r;
}

// async global->LDS, 16B per lane; lds dst = wave-uniform base + lane*16
__device__ __forceinline__ void gl16(const u16* g, u16* l) {
    __builtin_amdgcn_global_load_lds((const __attribute__((address_space(1))) void*)g,
                                     (__attribute__((address_space(3))) void*)l,
                                     16, 0, 0);
}

// ---------------------------------------------------------------------------
// GroupNorm stats: one block per (b,g); mean/var over H*W*(C/G) = 65536 f32
// ---------------------------------------------------------------------------
__global__ __launch_bounds__(256) void gn_stats_k(const float* __restrict__ x,
                                                  float* __restrict__ stats) {
    int bg = blockIdx.x;               // 0..127
    int b = bg >> 5, g = bg & 31;
    const size_t base = (size_t)b * 4096 * 512 + g * 16;
    int t = threadIdx.x;
    float s = 0.f, ss = 0.f;
    for (int it = 0; it < 64; ++it) {
        int vi = it * 256 + t;         // 16384 float4 vectors
        int n = vi >> 2;               // token 0..4095
        int j = (vi & 3) * 4;          // channel-within-group 0,4,8,12
        float4 u = *(const float4*)(x + base + (size_t)n * 512 + j);
        s += u.x + u.y + u.z + u.w;
        ss += u.x * u.x + u.y * u.y + u.z * u.z + u.w * u.w;
    }
    for (int off = 32; off; off >>= 1) {
        s  += __shfl_down(s, off, 64);
        ss += __shfl_down(ss, off, 64);
    }
    __shared__ float rs[4], rss[4];
    int lane = t & 63, w = t >> 6;
    if (lane == 0) { rs[w] = s; rss[w] = ss; }
    __syncthreads();
    if (t == 0) {
        float S1 = rs[0] + rs[1] + rs[2] + rs[3];
        float S2 = rss[0] + rss[1] + rss[2] + rss[3];
        float mean = S1 * (1.f / 65536.f);
        float var  = S2 * (1.f / 65536.f) - mean * mean;
        stats[2 * bg]     = mean;
        stats[2 * bg + 1] = rsqrtf(var + 1e-6f);
    }
}

// ---------------------------------------------------------------------------
// GroupNorm apply: h(bf16) = (x - mean) * rstd * gamma + beta, 4 f32/thread
// ---------------------------------------------------------------------------
__global__ __launch_bounds__(256) void gn_apply_k(const float* __restrict__ x,
                                                  const float* __restrict__ gamma,
                                                  const float* __restrict__ beta,
                                                  const float* __restrict__ stats,
                                                  u16* __restrict__ h) {
    size_t v = (size_t)blockIdx.x * 256 + threadIdx.x;   // float4 index
    size_t e = v * 4;
    int c = (int)(e & 511);            // multiple of 4; never crosses 16-ch group
    int b = (int)(e >> 21);            // e / (4096*512)
    int g = c >> 4;
    float mean = stats[2 * (b * 32 + g)];
    float rstd = stats[2 * (b * 32 + g) + 1];
    float4 xv = *(const float4*)(x + e);
    float4 gv = *(const float4*)(gamma + c);
    float4 bv = *(const float4*)(beta + c);
    ushort4 o;
    o.x = f2b((xv.x - mean) * rstd * gv.x + bv.x);
    o.y = f2b((xv.y - mean) * rstd * gv.y + bv.y);
    o.z = f2b((xv.z - mean) * rstd * gv.z + bv.z);
    o.w = f2b((xv.w - mean) * rstd * gv.w + bv.w);
    *(ushort4*)(h + e) = o;
}

// ---------------------------------------------------------------------------
// 512x512 fp32 -> bf16 transposed copy (for weight matrices)
// ---------------------------------------------------------------------------
__global__ __launch_bounds__(256) void transpose_f2b(const float* __restrict__ src,
                                                     u16* __restrict__ dst) {
    __shared__ float tile[32][33];
    int tx = threadIdx.x, ty = threadIdx.y;   // (32,8)
    int r0 = blockIdx.x * 32, c0 = blockIdx.y * 32;
#pragma unroll
    for (int i = 0; i < 4; ++i)
        tile[ty + i * 8][tx] = src[(size_t)(r0 + ty + i * 8) * 512 + c0 + tx];
    __syncthreads();
#pragma unroll
    for (int i = 0; i < 4; ++i)
        dst[(size_t)(c0 + ty + i * 8) * 512 + r0 + tx] = f2b(tile[tx][ty + i * 8]);
}

// ---------------------------------------------------------------------------
// bf16 -> bf16 transposed copy (V tiles), batched via blockIdx.z
// ---------------------------------------------------------------------------
__global__ __launch_bounds__(256) void transpose_b2b(const u16* __restrict__ src,
                                                     u16* __restrict__ dst,
                                                     int src_ld, int dst_ld,
                                                     long long sSrc, long long sDst) {
    __shared__ u16 tile[32][33];
    src += (size_t)blockIdx.z * sSrc;
    dst += (size_t)blockIdx.z * sDst;
    int tx = threadIdx.x, ty = threadIdx.y;   // (32,8)
    int r0 = blockIdx.x * 32, c0 = blockIdx.y * 32;
#pragma unroll
    for (int i = 0; i < 4; ++i)
        tile[ty + i * 8][tx] = src[(size_t)(r0 + ty + i * 8) * src_ld + c0 + tx];
    __syncthreads();
#pragma unroll
    for (int i = 0; i < 4; ++i)
        dst[(size_t)(c0 + ty + i * 8) * dst_ld + r0 + tx] = tile[tx][ty + i * 8];
}

__global__ __launch_bounds__(256) void concat_bias_f(const float* __restrict__ bq,
                                                     const float* __restrict__ bk,
                                                     const float* __restrict__ bv,
                                                     float* __restrict__ dst) {
    int i = blockIdx.x * 256 + threadIdx.x;   // 1536
    const float* src = (i < 512) ? bq : (i < 1024) ? bk : bv;
    dst[i] = src[i & 511];
}

// ---------------------------------------------------------------------------
// GEMM, C = scale*(A @ B^T) + bias (+resid), bf16 operands, fp32 accum.
// global_load_lds(16B) staging. Output bf16 to C or fp32 to Cf. 128x128 tile.
// ---------------------------------------------------------------------------
__global__ __launch_bounds__(256) void gemm_bt(const u16* __restrict__ A, int lda,
                                               const u16* __restrict__ B, int ldb,
                                               u16* __restrict__ C, float* __restrict__ Cf,
                                               int ldc,
                                               const float* __restrict__ bias,
                                               const float* __restrict__ resid,
                                               int K, float scale) {
    __shared__ u16 As[128 * 32];
    __shared__ u16 Bs[128 * 32];
    const int t = threadIdx.x;
    const int lane = t & 63, w = t >> 6;
    const int wm = (w >> 1) * 64, wn = (w & 1) * 64;
    const int r = lane & 15, q = lane >> 4;
    const int m0 = blockIdx.x * 128;
    const int n0 = blockIdx.y * 128;

    floatx4 acc[4][4];
#pragma unroll
    for (int mi = 0; mi < 4; ++mi)
#pragma unroll
        for (int ni = 0; ni < 4; ++ni) acc[mi][ni] = (floatx4){0.f, 0.f, 0.f, 0.f};

    const int srow = lane >> 2;
    const int scol = (lane & 3) * 8;
    const u16* gA = A + (size_t)(m0 + w * 32 + srow) * lda + scol;
    const u16* gB = B + (size_t)(n0 + w * 32 + srow) * ldb + scol;
    u16* lA = As + w * 1024;
    u16* lB = Bs + w * 1024;

    for (int k0 = 0; k0 < K; k0 += 32) {
        __syncthreads();
        gl16(gA,                     lA);
        gl16(gA + (size_t)16 * lda,  lA + 512);
        gl16(gB,                     lB);
        gl16(gB + (size_t)16 * ldb,  lB + 512);
        gA += 32; gB += 32;
        __syncthreads();
        short8 af[4], bfr[4];
#pragma unroll
        for (int mi = 0; mi < 4; ++mi)
            af[mi] = *(const short8*)(As + (wm + mi * 16 + r) * 32 + q * 8);
#pragma unroll
        for (int ni = 0; ni < 4; ++ni)
            bfr[ni] = *(const short8*)(Bs + (wn + ni * 16 + r) * 32 + q * 8);
#pragma unroll
        for (int mi = 0; mi < 4; ++mi)
#pragma unroll
            for (int ni = 0; ni < 4; ++ni)
                acc[mi][ni] = __builtin_amdgcn_mfma_f32_16x16x32_bf16(af[mi], bfr[ni],
                                                                      acc[mi][ni], 0, 0, 0);
    }

#pragma unroll
    for (int ni = 0; ni < 4; ++ni) {
        int col = n0 + wn + ni * 16 + r;
        float bv = bias ? bias[col] : 0.f;
#pragma unroll
        for (int mi = 0; mi < 4; ++mi) {
            int rowb = m0 + wm + mi * 16 + q * 4;
#pragma unroll
            for (int i = 0; i < 4; ++i) {
                size_t off = (size_t)(rowb + i) * ldc + col;
                float v = acc[mi][ni][i] * scale + bv;
                if (resid) v += resid[off];
                if (Cf) Cf[off] = v;
                else    C[off] = f2b(v);
            }
        }
    }
}

// ---------------------------------------------------------------------------
// Fused flash attention v3: ao = softmax(Q K^T / sqrt(512)) V, per batch.
// Grid (64,4) remapped XCD-aware, 256 thr (4 waves), 64 Q-rows per block.
//
// R3 restructure (flash was LDS-BW + barrier-drain bound: 1.36MB/kt LDS
// traffic with 4x wave duplication of K AND V frags, 512 barriers):
//  * QK row-split (wave w owns rows w*16..+15, Q frags in regs) - unchanged.
//  * PV channel-split: wave w owns output channels w*128..+127. V^T frags
//    load DIRECT global->VGPR (each line read once per block; V never
//    touches LDS). P is block-shared LDS (same 16KB + swizzle as before).
//  * K quad-buffered (128KB): all 4 ch-groups of kt+1 staged in one burst
//    right after the P-barrier -> arrive during PV with ~2000cyc lead.
//    QK section has ZERO barriers. Only 2 barriers/kt total (kt-start: K
//    arrived + prev P reads done; post-P: P/alpha visible + K bufs free).
//  * Online softmax rescale made unconditional (exp2(0)=1 exact); alpha &
//    l broadcast via 512B LDS so all waves can scale their 64-row acc.
//  * XCD remap: batch pinned to an XCD pair so K/V (8MB) stay L2-resident.
// LDS traffic/kt: 1.36MB -> 0.72MB; barriers 16/kt -> 2/kt.
// ---------------------------------------------------------------------------
#define FLASH_SMEM 147968
__global__ __launch_bounds__(256, 1) void flash_k(const u16* __restrict__ qkv,
                                                  const u16* __restrict__ vt,
                                                  u16* __restrict__ ao) {
    extern __shared__ u16 smem[];
    u16* Ks = smem;                   // [4 g][4 sub][128 key][4 chunk swz][8 ch] = 128KB
    u16* Pl = smem + 65536;           // [64 row][128 key] swizzled, 16KB (shared)
    float* alpha_bc = (float*)(smem + 65536 + 8192);   // 64 f32
    float* l_bc     = alpha_bc + 64;                   // 64 f32
    const int t = threadIdx.x;
    const int lane = t & 63, w = t >> 6;
    const int r = lane & 15, q = lane >> 4;
    const int swz = (q ^ ((r >> 1) & 3)) * 8;   // K-frag chunk swizzle (R1)
    // XCD-aware remap (round-robin xcd = linear%8): batch b -> XCD pair {2b,2b+1}
    const int lin  = blockIdx.y * 64 + blockIdx.x;
    const int xcd  = lin & 7, slot = lin >> 3;        // slot 0..31
    const int b    = xcd >> 1;
    const int qt   = ((xcd & 1) << 5) | slot;         // 0..63
    const u16* qb = qkv + (size_t)b * 4096 * 1536;
    const u16* kb = qb + 512;
    const u16* vb = vt + (size_t)b * 512 * 4096;
    u16* aob = ao + (size_t)b * 4096 * 512;
    const int wch = w * 128;          // wave's output-channel slice (PV)

    // precomputed per-thread K-staging offsets (global swizzled source, R1)
    int koff[8];
#pragma unroll
    for (int j = 0; j < 8; ++j) {
        int u = t + j * 256;
        int key = (u & 511) >> 2;
        int sub = u >> 9;
        int c = ((u & 3) ^ ((key >> 1) & 3)) * 8;
        koff[j] = key * 1536 + sub * 32 + c;
    }
    auto stageK = [&](int g, int kt) {
#pragma unroll
        for (int j = 0; j < 8; ++j)
            gl16(kb + (size_t)kt * 196608 + g * 128 + koff[j],
                 Ks + g * 16384 + t * 8 + j * 2048);
    };

    // per-thread V-frag global offsets (wave's 128 ch x key quad q)
    int voff[8];
#pragma unroll
    for (int ni = 0; ni < 8; ++ni)
        voff[ni] = (wch + ni * 16 + r) * 4096 + q * 8;

    short8 V0[8], V1[8];
#define LOADV(VA, KT, KK)                                                     \
    do {                                                                      \
        _Pragma("unroll") for (int ni = 0; ni < 8; ++ni)                      \
            VA[ni] = *(const short8*)(vb + (size_t)voff[ni] + (KT) * 128 +    \
                                      (KK) * 32);                             \
    } while (0)

    // Q fragments in registers: Qreg[kit] = Q[qrow][kit*32 + q*8 .. +7]
    const int qrow = qt * 64 + w * 16 + r;
    short8 Qreg[16];
#pragma unroll
    for (int kit = 0; kit < 16; ++kit)
        Qreg[kit] = *(const short8*)(qb + (size_t)qrow * 1536 + kit * 32 + q * 8);

    floatx4 acc_o[32];                // [mi row-tile 0..3][ni ch-tile 0..7]
#pragma unroll
    for (int i = 0; i < 32; ++i) acc_o[i] = (floatx4){0.f, 0.f, 0.f, 0.f};
    float m_run = -3.0e38f, l_run = 0.f;
    const float sc2 = 0.06375872f;    // 512^-0.5 * log2(e)

    // prologue: stage K(kt=0) fully, prefetch V(kt=0,k=0)
    stageK(0, 0); stageK(1, 0); stageK(2, 0); stageK(3, 0);
    LOADV(V0, 0, 0);

    for (int kt = 0; kt < 32; ++kt) {
        __syncthreads();              // K(kt) arrived; prev PV's P reads done
        // ----- S^T = K_tile @ Q^T (no barriers; all 4 groups resident)
        floatx4 acc_s[8];
#pragma unroll
        for (int mi = 0; mi < 8; ++mi) acc_s[mi] = (floatx4){0.f, 0.f, 0.f, 0.f};
#pragma unroll
        for (int g = 0; g < 4; ++g) {
            const u16* kbase = Ks + g * 16384;
#pragma unroll
            for (int s = 0; s < 4; ++s) {
                const u16* sbase = kbase + s * 4096;
#pragma unroll
                for (int mi = 0; mi < 8; ++mi) {
                    short8 af = *(const short8*)(sbase + (mi * 16 + r) * 32 + swz);
                    acc_s[mi] = __builtin_amdgcn_mfma_f32_16x16x32_bf16(
                        af, Qreg[g * 4 + s], acc_s[mi], 0, 0, 0);
                }
            }
        }
        // ----- online softmax (lane owns Q-row qrow's column of S^T)
        float m_t = -3.0e38f;
#pragma unroll
        for (int mi = 0; mi < 8; ++mi)
#pragma unroll
            for (int i = 0; i < 4; ++i) m_t = fmaxf(m_t, acc_s[mi][i]);
        m_t = fmaxf(m_t, __shfl_xor(m_t, 16, 64));
        m_t = fmaxf(m_t, __shfl_xor(m_t, 32, 64));
        float m_new = fmaxf(m_run, m_t);
        float alpha = __builtin_amdgcn_exp2f((m_run - m_new) * sc2);  // ==1 if no update
        float m2 = m_new * sc2;
        float rs = 0.f;
#pragma unroll
        for (int mi = 0; mi < 8; ++mi)
#pragma unroll
            for (int i = 0; i < 4; ++i) {
                float pv = __builtin_amdgcn_exp2f(acc_s[mi][i] * sc2 - m2);
                acc_s[mi][i] = pv;
                rs += pv;
            }
        rs += __shfl_xor(rs, 16, 64);
        rs += __shfl_xor(rs, 32, 64);
        l_run = l_run * alpha + rs;
        m_run = m_new;
        if (q == 0) alpha_bc[w * 16 + r] = alpha;
        // ----- pack P -> bf16, shared LDS [64 row][128 key], XOR swizzle
#pragma unroll
        for (int mi = 0; mi < 8; ++mi) {
            uint2 vv;
            vv.x = (unsigned)f2b(acc_s[mi][0]) | ((unsigned)f2b(acc_s[mi][1]) << 16);
            vv.y = (unsigned)f2b(acc_s[mi][2]) | ((unsigned)f2b(acc_s[mi][3]) << 16);
            *(uint2*)(Pl + (w * 16 + r) * 128 +
                      (((2 * mi + (q >> 1)) ^ (r & 7)) * 8) + (q & 1) * 4) = vv;
        }
        __syncthreads();              // P+alpha visible; all K(kt) reads done
        // stage ALL of K(kt+1) now: arrives during PV + next barrier
        if (kt < 31) { stageK(0, kt + 1); stageK(1, kt + 1);
                       stageK(2, kt + 1); stageK(3, kt + 1); }
        // ----- rescale O by per-row alpha (broadcast)
#pragma unroll
        for (int mi = 0; mi < 4; ++mi) {
            float4 al = *(const float4*)(alpha_bc + mi * 16 + q * 4);
#pragma unroll
            for (int ni = 0; ni < 8; ++ni) {
                acc_o[mi * 8 + ni][0] *= al.x; acc_o[mi * 8 + ni][1] *= al.y;
                acc_o[mi * 8 + ni][2] *= al.z; acc_o[mi * 8 + ni][3] *= al.w;
            }
        }
        // ----- PV (channel-split, V direct-from-global, no barriers)
#define PVK(KK, VA)                                                           \
    do {                                                                      \
        short8 ap0 = *(const short8*)(Pl + (0 * 16 + r) * 128 +               \
                                      ((((KK)*4 + q) ^ (r & 7)) * 8));        \
        short8 ap1 = *(const short8*)(Pl + (1 * 16 + r) * 128 +               \
                                      ((((KK)*4 + q) ^ (r & 7)) * 8));        \
        short8 ap2 = *(const short8*)(Pl + (2 * 16 + r) * 128 +               \
                                      ((((KK)*4 + q) ^ (r & 7)) * 8));        \
        short8 ap3 = *(const short8*)(Pl + (3 * 16 + r) * 128 +               \
                                      ((((KK)*4 + q) ^ (r & 7)) * 8));        \
        _Pragma("unroll") for (int ni = 0; ni < 8; ++ni) {                    \
            acc_o[0 * 8 + ni] = __builtin_amdgcn_mfma_f32_16x16x32_bf16(      \
                ap0, VA[ni], acc_o[0 * 8 + ni], 0, 0, 0);                     \
            acc_o[1 * 8 + ni] = __builtin_amdgcn_mfma_f32_16x16x32_bf16(      \
                ap1, VA[ni], acc_o[1 * 8 + ni], 0, 0, 0);                     \
            acc_o[2 * 8 + ni] = __builtin_amdgcn_mfma_f32_16x16x32_bf16(      \
                ap2, VA[ni], acc_o[2 * 8 + ni], 0, 0, 0);                     \
            acc_o[3 * 8 + ni] = __builtin_amdgcn_mfma_f32_16x16x32_bf16(      \
                ap3, VA[ni], acc_o[3 * 8 + ni], 0, 0, 0);                     \
        }                                                                     \
    } while (0)
        LOADV(V1, kt, 1);
        PVK(0, V0);
        LOADV(V0, kt, 2);
        PVK(1, V1);
        LOADV(V1, kt, 3);
        PVK(2, V0);
        if (kt < 31) LOADV(V0, kt + 1, 0);
        PVK(3, V1);
    }
    // ----- epilogue: broadcast l, divide, store
    if (q == 0) l_bc[w * 16 + r] = l_run;
    __syncthreads();
#pragma unroll
    for (int mi = 0; mi < 4; ++mi) {
        float4 lv = *(const float4*)(l_bc + mi * 16 + q * 4);
        float i0 = 1.f / lv.x, i1 = 1.f / lv.y, i2 = 1.f / lv.z, i3 = 1.f / lv.w;
        int rowb = qt * 64 + mi * 16 + q * 4;
#pragma unroll
        for (int ni = 0; ni < 8; ++ni) {
            int col = wch + ni * 16 + r;
            aob[(size_t)(rowb + 0) * 512 + col] = f2b(acc_o[mi * 8 + ni][0] * i0);
            aob[(size_t)(rowb + 1) * 512 + col] = f2b(acc_o[mi * 8 + ni][1] * i1);
            aob[(size_t)(rowb + 2) * 512 + col] = f2b(acc_o[mi * 8 + ni][2] * i2);
            aob[(size_t)(rowb + 3) * 512 + col] = f2b(acc_o[mi * 8 + ni][3] * i3);
        }
    }
#undef PVK
#undef LOADV
}

// ---------------------------------------------------------------------------
extern "C" void kernel_launch(void* const* d_in, const int* in_sizes, int n_in,
                              void* d_out, int out_size, void* d_ws, size_t ws_size,
                              hipStream_t stream) {
    const float* x     = (const float*)d_in[0];
    const float* gamma = (const float*)d_in[1];
    const float* beta  = (const float*)d_in[2];
    const float* Wq    = (const float*)d_in[3];
    const float* bq    = (const float*)d_in[4];
    const float* Wk    = (const float*)d_in[5];
    const float* bk    = (const float*)d_in[6];
    const float* Wv    = (const float*)d_in[7];
    const float* bv    = (const float*)d_in[8];
    const float* Wo    = (const float*)d_in[9];
    const float* bo    = (const float*)d_in[10];
    float* out = (float*)d_out;

    // B=4, N=4096, C=512, G=32 — ws layout
    char* ws = (char*)d_ws;
    float* stats  = (float*)(ws);                        // 128*2 f32
    float* bqkv   = (float*)(ws + 4096);                 // 1536 f32
    u16*   wqkv_t = (u16*)(ws + 16384);                  // [1536,512]
    u16*   wo_t   = wqkv_t + (size_t)1536 * 512;
    u16*   h      = wo_t + (size_t)512 * 512;            // [16384,512] (aliased as ao)
    u16*   qkv    = h   + (size_t)16384 * 512;           // [16384,1536]
    u16*   vt     = qkv + (size_t)16384 * 1536;          // [4][512][4096]
    u16*   ao     = h;                                   // h dead after QKV GEMM

    const long long sQKV = (long long)4096 * 1536;
    const long long sVT  = (long long)512 * 4096;

    dim3 tblk(32, 8, 1);
    transpose_f2b<<<dim3(16, 16, 1), tblk, 0, stream>>>(Wq, wqkv_t);
    transpose_f2b<<<dim3(16, 16, 1), tblk, 0, stream>>>(Wk, wqkv_t + 512 * 512);
    transpose_f2b<<<dim3(16, 16, 1), tblk, 0, stream>>>(Wv, wqkv_t + 1024 * 512);
    transpose_f2b<<<dim3(16, 16, 1), tblk, 0, stream>>>(Wo, wo_t);
    concat_bias_f<<<6, 256, 0, stream>>>(bq, bk, bv, bqkv);

    gn_stats_k<<<128, 256, 0, stream>>>(x, stats);
    gn_apply_k<<<8192, 256, 0, stream>>>(x, gamma, beta, stats, h);

    // QKV: [16384,512] @ [512,1536] -> qkv (+bias)
    gemm_bt<<<dim3(128, 12, 1), 256, 0, stream>>>(h, 512, wqkv_t, 512,
                                                  qkv, nullptr, 1536, bqkv, nullptr,
                                                  512, 1.0f);
    // v -> vt[b][c][n]
    transpose_b2b<<<dim3(128, 16, 4), tblk, 0, stream>>>(qkv + 1024, vt, 1536, 4096,
                                                         sQKV, sVT);
    // fused attention -> ao
    hipFuncSetAttribute((const void*)flash_k,
                        hipFuncAttributeMaxDynamicSharedMemorySize, FLASH_SMEM);
    flash_k<<<dim3(64, 4, 1), 256, FLASH_SMEM, stream>>>(qkv, vt, ao);

    // out = ao @ Wo + bo + x   (fp32 output + bias + residual)
    gemm_bt<<<dim3(128, 4, 1), 256, 0, stream>>>(ao, 512, wo_t, 512,
                                                 nullptr, out, 512, bo, x,
                                                 512, 1.0f);
}

// Round 4
// 466.383 us; speedup vs baseline: 2.4765x; 2.4765x over previous
//
#include <hip/hip_runtime.h>
#include <stdint.h>

using u16 = unsigned short;
typedef __attribute__((ext_vector_type(8))) short short8;   // 8 bf16 (4 VGPRs) MFMA A/B frag
typedef __attribute__((ext_vector_type(4))) float floatx4;  // MFMA C/D frag

__device__ __forceinline__ float b2f(u16 s) {
    union { unsigned u; float f; } x; x.u = ((unsigned)s) << 16; return x.f;
}
__device__ __forceinline__ u16 f2b(float f) {
    unsigned u = __float_as_uint(f);
    unsigned r = (u + 0x7fffu + ((u >> 16) & 1u)) >> 16;  // RNE
    return (u16)r;
}

// async global->LDS, 16B per lane; lds dst = wave-uniform base + lane*16
__device__ __forceinline__ void gl16(const u16* g, u16* l) {
    __builtin_amdgcn_global_load_lds((const __attribute__((address_space(1))) void*)g,
                                     (__attribute__((address_space(3))) void*)l,
                                     16, 0, 0);
}

// ---------------------------------------------------------------------------
// GroupNorm stats: one block per (b,g); mean/var over H*W*(C/G) = 65536 f32
// ---------------------------------------------------------------------------
__global__ __launch_bounds__(256) void gn_stats_k(const float* __restrict__ x,
                                                  float* __restrict__ stats) {
    int bg = blockIdx.x;               // 0..127
    int b = bg >> 5, g = bg & 31;
    const size_t base = (size_t)b * 4096 * 512 + g * 16;
    int t = threadIdx.x;
    float s = 0.f, ss = 0.f;
    for (int it = 0; it < 64; ++it) {
        int vi = it * 256 + t;         // 16384 float4 vectors
        int n = vi >> 2;               // token 0..4095
        int j = (vi & 3) * 4;          // channel-within-group 0,4,8,12
        float4 u = *(const float4*)(x + base + (size_t)n * 512 + j);
        s += u.x + u.y + u.z + u.w;
        ss += u.x * u.x + u.y * u.y + u.z * u.z + u.w * u.w;
    }
    for (int off = 32; off; off >>= 1) {
        s  += __shfl_down(s, off, 64);
        ss += __shfl_down(ss, off, 64);
    }
    __shared__ float rs[4], rss[4];
    int lane = t & 63, w = t >> 6;
    if (lane == 0) { rs[w] = s; rss[w] = ss; }
    __syncthreads();
    if (t == 0) {
        float S1 = rs[0] + rs[1] + rs[2] + rs[3];
        float S2 = rss[0] + rss[1] + rss[2] + rss[3];
        float mean = S1 * (1.f / 65536.f);
        float var  = S2 * (1.f / 65536.f) - mean * mean;
        stats[2 * bg]     = mean;
        stats[2 * bg + 1] = rsqrtf(var + 1e-6f);
    }
}

// ---------------------------------------------------------------------------
// GroupNorm apply: h(bf16) = (x - mean) * rstd * gamma + beta, 4 f32/thread
// ---------------------------------------------------------------------------
__global__ __launch_bounds__(256) void gn_apply_k(const float* __restrict__ x,
                                                  const float* __restrict__ gamma,
                                                  const float* __restrict__ beta,
                                                  const float* __restrict__ stats,
                                                  u16* __restrict__ h) {
    size_t v = (size_t)blockIdx.x * 256 + threadIdx.x;   // float4 index
    size_t e = v * 4;
    int c = (int)(e & 511);            // multiple of 4; never crosses 16-ch group
    int b = (int)(e >> 21);            // e / (4096*512)
    int g = c >> 4;
    float mean = stats[2 * (b * 32 + g)];
    float rstd = stats[2 * (b * 32 + g) + 1];
    float4 xv = *(const float4*)(x + e);
    float4 gv = *(const float4*)(gamma + c);
    float4 bv = *(const float4*)(beta + c);
    ushort4 o;
    o.x = f2b((xv.x - mean) * rstd * gv.x + bv.x);
    o.y = f2b((xv.y - mean) * rstd * gv.y + bv.y);
    o.z = f2b((xv.z - mean) * rstd * gv.z + bv.z);
    o.w = f2b((xv.w - mean) * rstd * gv.w + bv.w);
    *(ushort4*)(h + e) = o;
}

// ---------------------------------------------------------------------------
// 512x512 fp32 -> bf16 transposed copy (for weight matrices)
// ---------------------------------------------------------------------------
__global__ __launch_bounds__(256) void transpose_f2b(const float* __restrict__ src,
                                                     u16* __restrict__ dst) {
    __shared__ float tile[32][33];
    int tx = threadIdx.x, ty = threadIdx.y;   // (32,8)
    int r0 = blockIdx.x * 32, c0 = blockIdx.y * 32;
#pragma unroll
    for (int i = 0; i < 4; ++i)
        tile[ty + i * 8][tx] = src[(size_t)(r0 + ty + i * 8) * 512 + c0 + tx];
    __syncthreads();
#pragma unroll
    for (int i = 0; i < 4; ++i)
        dst[(size_t)(c0 + ty + i * 8) * 512 + r0 + tx] = f2b(tile[tx][ty + i * 8]);
}

// ---------------------------------------------------------------------------
// bf16 -> bf16 transposed copy (V tiles), batched via blockIdx.z
// ---------------------------------------------------------------------------
__global__ __launch_bounds__(256) void transpose_b2b(const u16* __restrict__ src,
                                                     u16* __restrict__ dst,
                                                     int src_ld, int dst_ld,
                                                     long long sSrc, long long sDst) {
    __shared__ u16 tile[32][33];
    src += (size_t)blockIdx.z * sSrc;
    dst += (size_t)blockIdx.z * sDst;
    int tx = threadIdx.x, ty = threadIdx.y;   // (32,8)
    int r0 = blockIdx.x * 32, c0 = blockIdx.y * 32;
#pragma unroll
    for (int i = 0; i < 4; ++i)
        tile[ty + i * 8][tx] = src[(size_t)(r0 + ty + i * 8) * src_ld + c0 + tx];
    __syncthreads();
#pragma unroll
    for (int i = 0; i < 4; ++i)
        dst[(size_t)(c0 + ty + i * 8) * dst_ld + r0 + tx] = tile[tx][ty + i * 8];
}

__global__ __launch_bounds__(256) void concat_bias_f(const float* __restrict__ bq,
                                                     const float* __restrict__ bk,
                                                     const float* __restrict__ bv,
                                                     float* __restrict__ dst) {
    int i = blockIdx.x * 256 + threadIdx.x;   // 1536
    const float* src = (i < 512) ? bq : (i < 1024) ? bk : bv;
    dst[i] = src[i & 511];
}

// ---------------------------------------------------------------------------
// GEMM, C = scale*(A @ B^T) + bias (+resid), bf16 operands, fp32 accum.
// global_load_lds(16B) staging. Output bf16 to C or fp32 to Cf. 128x128 tile.
// ---------------------------------------------------------------------------
__global__ __launch_bounds__(256) void gemm_bt(const u16* __restrict__ A, int lda,
                                               const u16* __restrict__ B, int ldb,
                                               u16* __restrict__ C, float* __restrict__ Cf,
                                               int ldc,
                                               const float* __restrict__ bias,
                                               const float* __restrict__ resid,
                                               int K, float scale) {
    __shared__ u16 As[128 * 32];
    __shared__ u16 Bs[128 * 32];
    const int t = threadIdx.x;
    const int lane = t & 63, w = t >> 6;
    const int wm = (w >> 1) * 64, wn = (w & 1) * 64;
    const int r = lane & 15, q = lane >> 4;
    const int m0 = blockIdx.x * 128;
    const int n0 = blockIdx.y * 128;

    floatx4 acc[4][4];
#pragma unroll
    for (int mi = 0; mi < 4; ++mi)
#pragma unroll
        for (int ni = 0; ni < 4; ++ni) acc[mi][ni] = (floatx4){0.f, 0.f, 0.f, 0.f};

    const int srow = lane >> 2;
    const int scol = (lane & 3) * 8;
    const u16* gA = A + (size_t)(m0 + w * 32 + srow) * lda + scol;
    const u16* gB = B + (size_t)(n0 + w * 32 + srow) * ldb + scol;
    u16* lA = As + w * 1024;
    u16* lB = Bs + w * 1024;

    for (int k0 = 0; k0 < K; k0 += 32) {
        __syncthreads();
        gl16(gA,                     lA);
        gl16(gA + (size_t)16 * lda,  lA + 512);
        gl16(gB,                     lB);
        gl16(gB + (size_t)16 * ldb,  lB + 512);
        gA += 32; gB += 32;
        __syncthreads();
        short8 af[4], bfr[4];
#pragma unroll
        for (int mi = 0; mi < 4; ++mi)
            af[mi] = *(const short8*)(As + (wm + mi * 16 + r) * 32 + q * 8);
#pragma unroll
        for (int ni = 0; ni < 4; ++ni)
            bfr[ni] = *(const short8*)(Bs + (wn + ni * 16 + r) * 32 + q * 8);
#pragma unroll
        for (int mi = 0; mi < 4; ++mi)
#pragma unroll
            for (int ni = 0; ni < 4; ++ni)
                acc[mi][ni] = __builtin_amdgcn_mfma_f32_16x16x32_bf16(af[mi], bfr[ni],
                                                                      acc[mi][ni], 0, 0, 0);
    }

#pragma unroll
    for (int ni = 0; ni < 4; ++ni) {
        int col = n0 + wn + ni * 16 + r;
        float bv = bias ? bias[col] : 0.f;
#pragma unroll
        for (int mi = 0; mi < 4; ++mi) {
            int rowb = m0 + wm + mi * 16 + q * 4;
#pragma unroll
            for (int i = 0; i < 4; ++i) {
                size_t off = (size_t)(rowb + i) * ldc + col;
                float v = acc[mi][ni][i] * scale + bv;
                if (resid) v += resid[off];
                if (Cf) Cf[off] = v;
                else    C[off] = f2b(v);
            }
        }
    }
}

// ---------------------------------------------------------------------------
// Fused flash attention v4: ao = softmax(Q K^T / sqrt(512)) V, per batch.
// Grid (64,4), 256 thr (4 waves), 64 Q-rows per block.
//
// Structure = R2's proven staging pipeline (K/V double-buffered 32KB chunks
// via global_load_lds, stages issued one compute phase ahead, 8 barriers/kt)
// + R3's harness-verified channel-split PV math:
//  * QK row-split (wave w owns Q-rows w*16..+15, Q frags in regs, reads all
//    of K from LDS) - unchanged from R2.
//  * PV channel-split: wave w owns output channels w*128..+127 and reads
//    ONLY its 128-ch slice of V from LDS (V wave-duplication 4x -> 1x;
//    PV LDS reads 528KB -> 192KB per kt per block).
//  * P block-shared [64 rows][128 keys] LDS (16KB), same XOR swizzle.
//  * alpha & l broadcast via 512B LDS; rescale unconditional (exp2(0)=1).
// R3's direct-global V failed: vmcnt is one in-order queue, so waiting on V
// register loads drained the whole stageK prefetch burst (223 GB/s serial
// fetch) + 64 extra VGPRs spilled (WRITE_SIZE 16->43MB). Staying on the
// gl16 path avoids both.
// ---------------------------------------------------------------------------
#define FLASH_SMEM 147968
__global__ __launch_bounds__(256, 1) void flash_k(const u16* __restrict__ qkv,
                                                  const u16* __restrict__ vt,
                                                  u16* __restrict__ ao) {
    extern __shared__ u16 smem[];
    u16* Ks = smem;                 // 2 bufs x 16384 elems (2 x 32KB): [4 sub][128 key][4 chunk swz][8 ch]
    u16* Vs = smem + 32768;         // 2 bufs x 16384 elems (2 x 32KB): [512 ch][4 chunk swz][8 key]
    u16* Pl = smem + 65536;         // [64 row][128 key] swizzled, 16KB (block-shared)
    float* alpha_bc = (float*)(smem + 73728);   // 64 f32
    float* l_bc     = alpha_bc + 64;            // 64 f32
    const int t = threadIdx.x;
    const int lane = t & 63, w = t >> 6;
    const int r = lane & 15, q = lane >> 4;
    const int swz = (q ^ ((r >> 1) & 3)) * 8;   // K/V-frag chunk swizzle (R1)
    const int b = blockIdx.y, qt = blockIdx.x;
    const u16* qb = qkv + (size_t)b * 4096 * 1536;
    const u16* kb = qb + 512;
    const u16* vb = vt + (size_t)b * 512 * 4096;
    u16* aob = ao + (size_t)b * 4096 * 512;
    const int wch = w * 128;        // wave's output-channel slice (PV)

    auto stageK = [&](int buf, int kt, int g) {
#pragma unroll
        for (int j = 0; j < 8; ++j) {
            int u = t + j * 256;
            int key = (u & 511) >> 2;
            int sub = u >> 9;
            int c = ((u & 3) ^ ((key >> 1) & 3)) * 8;   // pre-swizzled source chunk
            gl16(kb + (size_t)(kt * 128 + key) * 1536 + g * 128 + sub * 32 + c,
                 Ks + buf * 16384 + u * 8);
        }
    };
    auto stageV = [&](int buf, int kt, int k) {
#pragma unroll
        for (int j = 0; j < 8; ++j) {
            int u = t + j * 256;
            int ch = u >> 2;
            int c = ((u & 3) ^ ((ch >> 1) & 3)) * 8;    // pre-swizzled source chunk
            gl16(vb + (size_t)ch * 4096 + kt * 128 + k * 32 + c,
                 Vs + buf * 16384 + u * 8);
        }
    };

    stageK(0, 0, 0);
    stageV(0, 0, 0);

    // Q fragments in registers: Qreg[kit] = Q[qrow][kit*32 + q*8 .. +7]
    const int qrow = qt * 64 + w * 16 + r;
    short8 Qreg[16];
#pragma unroll
    for (int kit = 0; kit < 16; ++kit)
        Qreg[kit] = *(const short8*)(qb + (size_t)qrow * 1536 + kit * 32 + q * 8);

    floatx4 acc_o[32];              // [mi row-tile 0..3][ni ch-tile 0..7]
#pragma unroll
    for (int i = 0; i < 32; ++i) acc_o[i] = (floatx4){0.f, 0.f, 0.f, 0.f};
    float m_run = -3.0e38f, l_run = 0.f;
    const float sc2 = 0.06375872f;  // 512^-0.5 * log2(e)

    for (int kt = 0; kt < 32; ++kt) {
        // ----- S^T = K_tile @ Q^T : acc_s[mi][i] = S[key=kt*128+mi*16+q*4+i][qrow]
        floatx4 acc_s[8];
#pragma unroll
        for (int mi = 0; mi < 8; ++mi) acc_s[mi] = (floatx4){0.f, 0.f, 0.f, 0.f};
#pragma unroll
        for (int g = 0; g < 4; ++g) {
            __syncthreads();                       // drains stage issued last phase
            if (g < 3) stageK((g + 1) & 1, kt, g + 1);
            const u16* kbase = Ks + (g & 1) * 16384;
#pragma unroll
            for (int s = 0; s < 4; ++s) {
                const u16* sbase = kbase + s * 4096;
#pragma unroll
                for (int mi = 0; mi < 8; ++mi) {
                    short8 af = *(const short8*)(sbase + (mi * 16 + r) * 32 + swz);
                    acc_s[mi] = __builtin_amdgcn_mfma_f32_16x16x32_bf16(
                        af, Qreg[g * 4 + s], acc_s[mi], 0, 0, 0);
                }
            }
        }
        // ----- online softmax (lane owns Q-row qrow's column of S^T)
        float m_t = -3.0e38f;
#pragma unroll
        for (int mi = 0; mi < 8; ++mi)
#pragma unroll
            for (int i = 0; i < 4; ++i) m_t = fmaxf(m_t, acc_s[mi][i]);
        m_t = fmaxf(m_t, __shfl_xor(m_t, 16, 64));
        m_t = fmaxf(m_t, __shfl_xor(m_t, 32, 64));
        float m_new = fmaxf(m_run, m_t);
        float alpha = __builtin_amdgcn_exp2f((m_run - m_new) * sc2);  // ==1 if no update
        float m2 = m_new * sc2;
        float rs = 0.f;
#pragma unroll
        for (int mi = 0; mi < 8; ++mi)
#pragma unroll
            for (int i = 0; i < 4; ++i) {
                float pv = __builtin_amdgcn_exp2f(acc_s[mi][i] * sc2 - m2);
                acc_s[mi][i] = pv;
                rs += pv;
            }
        rs += __shfl_xor(rs, 16, 64);
        rs += __shfl_xor(rs, 32, 64);
        l_run = l_run * alpha + rs;
        m_run = m_new;
        if (q == 0) alpha_bc[w * 16 + r] = alpha;
        // ----- pack P -> bf16, shared LDS [64 row][128 key], XOR swizzle
#pragma unroll
        for (int mi = 0; mi < 8; ++mi) {
            uint2 vv;
            vv.x = (unsigned)f2b(acc_s[mi][0]) | ((unsigned)f2b(acc_s[mi][1]) << 16);
            vv.y = (unsigned)f2b(acc_s[mi][2]) | ((unsigned)f2b(acc_s[mi][3]) << 16);
            *(uint2*)(Pl + (w * 16 + r) * 128 +
                      (((2 * mi + (q >> 1)) ^ (r & 7)) * 8) + (q & 1) * 4) = vv;
        }
        // ----- PV channel-split: acc_o[mi][ni] += P[mi-rows x 32k] @ V^T[wave ch x 32k]
#pragma unroll
        for (int k = 0; k < 4; ++k) {
            __syncthreads();         // P/alpha visible (k=0); V chunk arrived
            if (k < 3)        stageV((k + 1) & 1, kt, k + 1);
            else if (kt < 31) stageV(0, kt + 1, 0);
            if (k == 0 && kt < 31) stageK(0, kt + 1, 0);
            if (k == 0) {            // rescale O by per-row alpha (broadcast)
#pragma unroll
                for (int mi = 0; mi < 4; ++mi) {
                    float4 al = *(const float4*)(alpha_bc + mi * 16 + q * 4);
#pragma unroll
                    for (int ni = 0; ni < 8; ++ni) {
                        acc_o[mi * 8 + ni][0] *= al.x; acc_o[mi * 8 + ni][1] *= al.y;
                        acc_o[mi * 8 + ni][2] *= al.z; acc_o[mi * 8 + ni][3] *= al.w;
                    }
                }
            }
            short8 ap[4];
#pragma unroll
            for (int mi = 0; mi < 4; ++mi)
                ap[mi] = *(const short8*)(Pl + (mi * 16 + r) * 128 +
                                          (((k * 4 + q) ^ (r & 7)) * 8));
            const u16* vbase = Vs + (k & 1) * 16384;
#pragma unroll
            for (int ni = 0; ni < 8; ++ni) {
                short8 bf = *(const short8*)(vbase + (wch + ni * 16 + r) * 32 + swz);
#pragma unroll
                for (int mi = 0; mi < 4; ++mi)
                    acc_o[mi * 8 + ni] = __builtin_amdgcn_mfma_f32_16x16x32_bf16(
                        ap[mi], bf, acc_o[mi * 8 + ni], 0, 0, 0);
            }
        }
    }
    // ----- epilogue: broadcast l, divide, store (row mi*16+q*4+i, col wch+ni*16+r)
    if (q == 0) l_bc[w * 16 + r] = l_run;
    __syncthreads();
#pragma unroll
    for (int mi = 0; mi < 4; ++mi) {
        float4 lv = *(const float4*)(l_bc + mi * 16 + q * 4);
        float i0 = 1.f / lv.x, i1 = 1.f / lv.y, i2 = 1.f / lv.z, i3 = 1.f / lv.w;
        int rowb = qt * 64 + mi * 16 + q * 4;
#pragma unroll
        for (int ni = 0; ni < 8; ++ni) {
            int col = wch + ni * 16 + r;
            aob[(size_t)(rowb + 0) * 512 + col] = f2b(acc_o[mi * 8 + ni][0] * i0);
            aob[(size_t)(rowb + 1) * 512 + col] = f2b(acc_o[mi * 8 + ni][1] * i1);
            aob[(size_t)(rowb + 2) * 512 + col] = f2b(acc_o[mi * 8 + ni][2] * i2);
            aob[(size_t)(rowb + 3) * 512 + col] = f2b(acc_o[mi * 8 + ni][3] * i3);
        }
    }
}

// ---------------------------------------------------------------------------
extern "C" void kernel_launch(void* const* d_in, const int* in_sizes, int n_in,
                              void* d_out, int out_size, void* d_ws, size_t ws_size,
                              hipStream_t stream) {
    const float* x     = (const float*)d_in[0];
    const float* gamma = (const float*)d_in[1];
    const float* beta  = (const float*)d_in[2];
    const float* Wq    = (const float*)d_in[3];
    const float* bq    = (const float*)d_in[4];
    const float* Wk    = (const float*)d_in[5];
    const float* bk    = (const float*)d_in[6];
    const float* Wv    = (const float*)d_in[7];
    const float* bv    = (const float*)d_in[8];
    const float* Wo    = (const float*)d_in[9];
    const float* bo    = (const float*)d_in[10];
    float* out = (float*)d_out;

    // B=4, N=4096, C=512, G=32 — ws layout
    char* ws = (char*)d_ws;
    float* stats  = (float*)(ws);                        // 128*2 f32
    float* bqkv   = (float*)(ws + 4096);                 // 1536 f32
    u16*   wqkv_t = (u16*)(ws + 16384);                  // [1536,512]
    u16*   wo_t   = wqkv_t + (size_t)1536 * 512;
    u16*   h      = wo_t + (size_t)512 * 512;            // [16384,512] (aliased as ao)
    u16*   qkv    = h   + (size_t)16384 * 512;           // [16384,1536]
    u16*   vt     = qkv + (size_t)16384 * 1536;          // [4][512][4096]
    u16*   ao     = h;                                   // h dead after QKV GEMM

    const long long sQKV = (long long)4096 * 1536;
    const long long sVT  = (long long)512 * 4096;

    dim3 tblk(32, 8, 1);
    transpose_f2b<<<dim3(16, 16, 1), tblk, 0, stream>>>(Wq, wqkv_t);
    transpose_f2b<<<dim3(16, 16, 1), tblk, 0, stream>>>(Wk, wqkv_t + 512 * 512);
    transpose_f2b<<<dim3(16, 16, 1), tblk, 0, stream>>>(Wv, wqkv_t + 1024 * 512);
    transpose_f2b<<<dim3(16, 16, 1), tblk, 0, stream>>>(Wo, wo_t);
    concat_bias_f<<<6, 256, 0, stream>>>(bq, bk, bv, bqkv);

    gn_stats_k<<<128, 256, 0, stream>>>(x, stats);
    gn_apply_k<<<8192, 256, 0, stream>>>(x, gamma, beta, stats, h);

    // QKV: [16384,512] @ [512,1536] -> qkv (+bias)
    gemm_bt<<<dim3(128, 12, 1), 256, 0, stream>>>(h, 512, wqkv_t, 512,
                                                  qkv, nullptr, 1536, bqkv, nullptr,
                                                  512, 1.0f);
    // v -> vt[b][c][n]
    transpose_b2b<<<dim3(128, 16, 4), tblk, 0, stream>>>(qkv + 1024, vt, 1536, 4096,
                                                         sQKV, sVT);
    // fused attention -> ao
    hipFuncSetAttribute((const void*)flash_k,
                        hipFuncAttributeMaxDynamicSharedMemorySize, FLASH_SMEM);
    flash_k<<<dim3(64, 4, 1), 256, FLASH_SMEM, stream>>>(qkv, vt, ao);

    // out = ao @ Wo + bo + x   (fp32 output + bias + residual)
    gemm_bt<<<dim3(128, 4, 1), 256, 0, stream>>>(ao, 512, wo_t, 512,
                                                 nullptr, out, 512, bo, x,
                                                 512, 1.0f);
}

// Round 5
// 437.311 us; speedup vs baseline: 2.6412x; 1.0665x over previous
//
#include <hip/hip_runtime.h>
#include <stdint.h>

using u16 = unsigned short;
typedef __attribute__((ext_vector_type(8))) short short8;   // 8 bf16 (4 VGPRs) MFMA A/B frag
typedef __attribute__((ext_vector_type(4))) float floatx4;  // MFMA C/D frag

__device__ __forceinline__ float b2f(u16 s) {
    union { unsigned u; float f; } x; x.u = ((unsigned)s) << 16; return x.f;
}
__device__ __forceinline__ u16 f2b(float f) {
    unsigned u = __float_as_uint(f);
    unsigned r = (u + 0x7fffu + ((u >> 16) & 1u)) >> 16;  // RNE
    return (u16)r;
}

// async global->LDS, 16B per lane; lds dst = wave-uniform base + lane*16
__device__ __forceinline__ void gl16(const u16* g, u16* l) {
    __builtin_amdgcn_global_load_lds((const __attribute__((address_space(1))) void*)g,
                                     (__attribute__((address_space(3))) void*)l,
                                     16, 0, 0);
}

// ---------------------------------------------------------------------------
// GroupNorm stats: one block per (b,g); mean/var over H*W*(C/G) = 65536 f32
// ---------------------------------------------------------------------------
__global__ __launch_bounds__(256) void gn_stats_k(const float* __restrict__ x,
                                                  float* __restrict__ stats) {
    int bg = blockIdx.x;               // 0..127
    int b = bg >> 5, g = bg & 31;
    const size_t base = (size_t)b * 4096 * 512 + g * 16;
    int t = threadIdx.x;
    float s = 0.f, ss = 0.f;
    for (int it = 0; it < 64; ++it) {
        int vi = it * 256 + t;         // 16384 float4 vectors
        int n = vi >> 2;               // token 0..4095
        int j = (vi & 3) * 4;          // channel-within-group 0,4,8,12
        float4 u = *(const float4*)(x + base + (size_t)n * 512 + j);
        s += u.x + u.y + u.z + u.w;
        ss += u.x * u.x + u.y * u.y + u.z * u.z + u.w * u.w;
    }
    for (int off = 32; off; off >>= 1) {
        s  += __shfl_down(s, off, 64);
        ss += __shfl_down(ss, off, 64);
    }
    __shared__ float rs[4], rss[4];
    int lane = t & 63, w = t >> 6;
    if (lane == 0) { rs[w] = s; rss[w] = ss; }
    __syncthreads();
    if (t == 0) {
        float S1 = rs[0] + rs[1] + rs[2] + rs[3];
        float S2 = rss[0] + rss[1] + rss[2] + rss[3];
        float mean = S1 * (1.f / 65536.f);
        float var  = S2 * (1.f / 65536.f) - mean * mean;
        stats[2 * bg]     = mean;
        stats[2 * bg + 1] = rsqrtf(var + 1e-6f);
    }
}

// ---------------------------------------------------------------------------
// GroupNorm apply: h(bf16) = (x - mean) * rstd * gamma + beta, 4 f32/thread
// ---------------------------------------------------------------------------
__global__ __launch_bounds__(256) void gn_apply_k(const float* __restrict__ x,
                                                  const float* __restrict__ gamma,
                                                  const float* __restrict__ beta,
                                                  const float* __restrict__ stats,
                                                  u16* __restrict__ h) {
    size_t v = (size_t)blockIdx.x * 256 + threadIdx.x;   // float4 index
    size_t e = v * 4;
    int c = (int)(e & 511);            // multiple of 4; never crosses 16-ch group
    int b = (int)(e >> 21);            // e / (4096*512)
    int g = c >> 4;
    float mean = stats[2 * (b * 32 + g)];
    float rstd = stats[2 * (b * 32 + g) + 1];
    float4 xv = *(const float4*)(x + e);
    float4 gv = *(const float4*)(gamma + c);
    float4 bv = *(const float4*)(beta + c);
    ushort4 o;
    o.x = f2b((xv.x - mean) * rstd * gv.x + bv.x);
    o.y = f2b((xv.y - mean) * rstd * gv.y + bv.y);
    o.z = f2b((xv.z - mean) * rstd * gv.z + bv.z);
    o.w = f2b((xv.w - mean) * rstd * gv.w + bv.w);
    *(ushort4*)(h + e) = o;
}

// ---------------------------------------------------------------------------
// 512x512 fp32 -> bf16 transposed copy (for weight matrices)
// ---------------------------------------------------------------------------
__global__ __launch_bounds__(256) void transpose_f2b(const float* __restrict__ src,
                                                     u16* __restrict__ dst) {
    __shared__ float tile[32][33];
    int tx = threadIdx.x, ty = threadIdx.y;   // (32,8)
    int r0 = blockIdx.x * 32, c0 = blockIdx.y * 32;
#pragma unroll
    for (int i = 0; i < 4; ++i)
        tile[ty + i * 8][tx] = src[(size_t)(r0 + ty + i * 8) * 512 + c0 + tx];
    __syncthreads();
#pragma unroll
    for (int i = 0; i < 4; ++i)
        dst[(size_t)(c0 + ty + i * 8) * 512 + r0 + tx] = f2b(tile[tx][ty + i * 8]);
}

// ---------------------------------------------------------------------------
// bf16 -> bf16 transposed copy (V tiles), batched via blockIdx.z
// ---------------------------------------------------------------------------
__global__ __launch_bounds__(256) void transpose_b2b(const u16* __restrict__ src,
                                                     u16* __restrict__ dst,
                                                     int src_ld, int dst_ld,
                                                     long long sSrc, long long sDst) {
    __shared__ u16 tile[32][33];
    src += (size_t)blockIdx.z * sSrc;
    dst += (size_t)blockIdx.z * sDst;
    int tx = threadIdx.x, ty = threadIdx.y;   // (32,8)
    int r0 = blockIdx.x * 32, c0 = blockIdx.y * 32;
#pragma unroll
    for (int i = 0; i < 4; ++i)
        tile[ty + i * 8][tx] = src[(size_t)(r0 + ty + i * 8) * src_ld + c0 + tx];
    __syncthreads();
#pragma unroll
    for (int i = 0; i < 4; ++i)
        dst[(size_t)(c0 + ty + i * 8) * dst_ld + r0 + tx] = tile[tx][ty + i * 8];
}

__global__ __launch_bounds__(256) void concat_bias_f(const float* __restrict__ bq,
                                                     const float* __restrict__ bk,
                                                     const float* __restrict__ bv,
                                                     float* __restrict__ dst) {
    int i = blockIdx.x * 256 + threadIdx.x;   // 1536
    const float* src = (i < 512) ? bq : (i < 1024) ? bk : bv;
    dst[i] = src[i & 511];
}

// ---------------------------------------------------------------------------
// GEMM, C = scale*(A @ B^T) + bias (+resid), bf16 operands, fp32 accum.
// global_load_lds(16B) staging. Output bf16 to C or fp32 to Cf. 128x128 tile.
// ---------------------------------------------------------------------------
__global__ __launch_bounds__(256) void gemm_bt(const u16* __restrict__ A, int lda,
                                               const u16* __restrict__ B, int ldb,
                                               u16* __restrict__ C, float* __restrict__ Cf,
                                               int ldc,
                                               const float* __restrict__ bias,
                                               const float* __restrict__ resid,
                                               int K, float scale) {
    __shared__ u16 As[128 * 32];
    __shared__ u16 Bs[128 * 32];
    const int t = threadIdx.x;
    const int lane = t & 63, w = t >> 6;
    const int wm = (w >> 1) * 64, wn = (w & 1) * 64;
    const int r = lane & 15, q = lane >> 4;
    const int m0 = blockIdx.x * 128;
    const int n0 = blockIdx.y * 128;

    floatx4 acc[4][4];
#pragma unroll
    for (int mi = 0; mi < 4; ++mi)
#pragma unroll
        for (int ni = 0; ni < 4; ++ni) acc[mi][ni] = (floatx4){0.f, 0.f, 0.f, 0.f};

    const int srow = lane >> 2;
    const int scol = (lane & 3) * 8;
    const u16* gA = A + (size_t)(m0 + w * 32 + srow) * lda + scol;
    const u16* gB = B + (size_t)(n0 + w * 32 + srow) * ldb + scol;
    u16* lA = As + w * 1024;
    u16* lB = Bs + w * 1024;

    for (int k0 = 0; k0 < K; k0 += 32) {
        __syncthreads();
        gl16(gA,                     lA);
        gl16(gA + (size_t)16 * lda,  lA + 512);
        gl16(gB,                     lB);
        gl16(gB + (size_t)16 * ldb,  lB + 512);
        gA += 32; gB += 32;
        __syncthreads();
        short8 af[4], bfr[4];
#pragma unroll
        for (int mi = 0; mi < 4; ++mi)
            af[mi] = *(const short8*)(As + (wm + mi * 16 + r) * 32 + q * 8);
#pragma unroll
        for (int ni = 0; ni < 4; ++ni)
            bfr[ni] = *(const short8*)(Bs + (wn + ni * 16 + r) * 32 + q * 8);
#pragma unroll
        for (int mi = 0; mi < 4; ++mi)
#pragma unroll
            for (int ni = 0; ni < 4; ++ni)
                acc[mi][ni] = __builtin_amdgcn_mfma_f32_16x16x32_bf16(af[mi], bfr[ni],
                                                                      acc[mi][ni], 0, 0, 0);
    }

#pragma unroll
    for (int ni = 0; ni < 4; ++ni) {
        int col = n0 + wn + ni * 16 + r;
        float bv = bias ? bias[col] : 0.f;
#pragma unroll
        for (int mi = 0; mi < 4; ++mi) {
            int rowb = m0 + wm + mi * 16 + q * 4;
#pragma unroll
            for (int i = 0; i < 4; ++i) {
                size_t off = (size_t)(rowb + i) * ldc + col;
                float v = acc[mi][ni][i] * scale + bv;
                if (resid) v += resid[off];
                if (Cf) Cf[off] = v;
                else    C[off] = f2b(v);
            }
        }
    }
}

// ---------------------------------------------------------------------------
// Fused flash attention v5: ao = softmax(Q K^T / sqrt(512)) V, per batch.
// Grid (64,4) = 256 blocks, 512 thr (8 waves) -> 2 waves/SIMD (was 1).
//
// R4 was LDS-pipe (~130us floor) + ~120us exposed stalls at 1 wave/SIMD.
// v5 keeps R4's exact phase/staging schedule but splits the block's work
// across 8 waves so 2 waves per SIMD cover each other's latency:
//  * QK 4x2 split: wave = (row-tile rw = w&3, key-half kh = w>>2); each wave
//    computes S^T for its 16 Q-rows x 64 keys (acc_s[4], Qreg[16] as before).
//  * Softmax: partner waves (w^4) exchange per-row tile-max via 512B LDS +
//    one barrier (vmcnt queue empty there -> cheap). Both partners compute
//    identical m_new/alpha; l kept as per-key-half l_half, summed in the
//    epilogue (no per-kt l exchange).
//  * PV 8-way channel-split: wave owns 64 output channels; acc_o 128->64
//    VGPRs, rescale VALU halves. V/P LDS read totals unchanged.
//  * P pack: chunk index gains kh*8 term; same XOR-by-(r&7) swizzle, read
//    side unchanged (bijective per row).
// Staging (gl16 only, R3 lesson), chunk sizes, and barrier placement are
// identical to R4; one extra barrier/kt for the max exchange (9 total).
// ---------------------------------------------------------------------------
#define FLASH_SMEM 148224
__global__ __launch_bounds__(512, 2) void flash_k(const u16* __restrict__ qkv,
                                                  const u16* __restrict__ vt,
                                                  u16* __restrict__ ao) {
    extern __shared__ u16 smem[];
    u16* Ks = smem;                 // 2 bufs x 16384: [4 sub][128 key][4 chunk swz][8 ch]
    u16* Vs = smem + 32768;         // 2 bufs x 16384: [512 ch][4 chunk swz][8 key]
    u16* Pl = smem + 65536;         // [64 row][128 key] swizzled, 16KB (block-shared)
    float* alpha_bc = (float*)(smem + 73728);   // 64 f32
    float* mexl     = alpha_bc + 64;            // 128 f32: m exchange / l exchange
    const int t = threadIdx.x;
    const int lane = t & 63, w = t >> 6;        // w 0..7
    const int rw = w & 3, kh = w >> 2;          // QK row-tile, key-half
    const int r = lane & 15, q = lane >> 4;
    const int swz = (q ^ ((r >> 1) & 3)) * 8;   // K/V-frag chunk swizzle (R1)
    const int b = blockIdx.y, qt = blockIdx.x;
    const u16* qb = qkv + (size_t)b * 4096 * 1536;
    const u16* kb = qb + 512;
    const u16* vb = vt + (size_t)b * 512 * 4096;
    u16* aob = ao + (size_t)b * 4096 * 512;
    const int wch = w * 64;         // wave's output-channel slice (PV)

    auto stageK = [&](int buf, int kt, int g) {
#pragma unroll
        for (int j = 0; j < 4; ++j) {
            int u = t + j * 512;
            int key = (u & 511) >> 2;
            int sub = u >> 9;
            int c = ((u & 3) ^ ((key >> 1) & 3)) * 8;   // pre-swizzled source chunk
            gl16(kb + (size_t)(kt * 128 + key) * 1536 + g * 128 + sub * 32 + c,
                 Ks + buf * 16384 + u * 8);
        }
    };
    auto stageV = [&](int buf, int kt, int k) {
#pragma unroll
        for (int j = 0; j < 4; ++j) {
            int u = t + j * 512;
            int ch = u >> 2;
            int c = ((u & 3) ^ ((ch >> 1) & 3)) * 8;    // pre-swizzled source chunk
            gl16(vb + (size_t)ch * 4096 + kt * 128 + k * 32 + c,
                 Vs + buf * 16384 + u * 8);
        }
    };

    stageK(0, 0, 0);
    stageV(0, 0, 0);

    // Q fragments in registers: Qreg[kit] = Q[qrow][kit*32 + q*8 .. +7]
    const int qrow = qt * 64 + rw * 16 + r;
    short8 Qreg[16];
#pragma unroll
    for (int kit = 0; kit < 16; ++kit)
        Qreg[kit] = *(const short8*)(qb + (size_t)qrow * 1536 + kit * 32 + q * 8);

    floatx4 acc_o[16];              // [mi row-tile 0..3][ni ch-tile 0..3]
#pragma unroll
    for (int i = 0; i < 16; ++i) acc_o[i] = (floatx4){0.f, 0.f, 0.f, 0.f};
    float m_run = -3.0e38f, l_half = 0.f;
    const float sc2 = 0.06375872f;  // 512^-0.5 * log2(e)

    for (int kt = 0; kt < 32; ++kt) {
        // ----- S^T = K_tile @ Q^T for wave's (64 keys x 16 rows) block
        floatx4 acc_s[4];
#pragma unroll
        for (int mi = 0; mi < 4; ++mi) acc_s[mi] = (floatx4){0.f, 0.f, 0.f, 0.f};
#pragma unroll
        for (int g = 0; g < 4; ++g) {
            __syncthreads();                       // drains stage issued last phase
            if (g < 3) stageK((g + 1) & 1, kt, g + 1);
            const u16* kbase = Ks + (g & 1) * 16384;
#pragma unroll
            for (int s = 0; s < 4; ++s) {
                const u16* sbase = kbase + s * 4096;
#pragma unroll
                for (int mi = 0; mi < 4; ++mi) {
                    short8 af = *(const short8*)(sbase + (kh * 64 + mi * 16 + r) * 32 + swz);
                    acc_s[mi] = __builtin_amdgcn_mfma_f32_16x16x32_bf16(
                        af, Qreg[g * 4 + s], acc_s[mi], 0, 0, 0);
                }
            }
        }
        // ----- online softmax; lane owns Q-row (rw*16+r), keys kh*64..+63
        float m_t = -3.0e38f;
#pragma unroll
        for (int mi = 0; mi < 4; ++mi)
#pragma unroll
            for (int i = 0; i < 4; ++i) m_t = fmaxf(m_t, acc_s[mi][i]);
        m_t = fmaxf(m_t, __shfl_xor(m_t, 16, 64));
        m_t = fmaxf(m_t, __shfl_xor(m_t, 32, 64));
        if (q == 0) mexl[w * 16 + r] = m_t;
        __syncthreads();               // exchange with partner (vmcnt queue empty)
        float m_t2 = mexl[(w ^ 4) * 16 + r];
        float m_new = fmaxf(m_run, fmaxf(m_t, m_t2));
        float alpha = __builtin_amdgcn_exp2f((m_run - m_new) * sc2);  // identical in partners
        float m2 = m_new * sc2;
        float rs = 0.f;
#pragma unroll
        for (int mi = 0; mi < 4; ++mi)
#pragma unroll
            for (int i = 0; i < 4; ++i) {
                float pv = __builtin_amdgcn_exp2f(acc_s[mi][i] * sc2 - m2);
                acc_s[mi][i] = pv;
                rs += pv;
            }
        rs += __shfl_xor(rs, 16, 64);
        rs += __shfl_xor(rs, 32, 64);
        l_half = l_half * alpha + rs;
        m_run = m_new;
        if (kh == 0 && q == 0) alpha_bc[rw * 16 + r] = alpha;
        // ----- pack P -> bf16, shared LDS [64 row][128 key], XOR swizzle
#pragma unroll
        for (int mi = 0; mi < 4; ++mi) {
            uint2 vv;
            vv.x = (unsigned)f2b(acc_s[mi][0]) | ((unsigned)f2b(acc_s[mi][1]) << 16);
            vv.y = (unsigned)f2b(acc_s[mi][2]) | ((unsigned)f2b(acc_s[mi][3]) << 16);
            *(uint2*)(Pl + (rw * 16 + r) * 128 +
                      (((kh * 8 + 2 * mi + (q >> 1)) ^ (r & 7)) * 8) + (q & 1) * 4) = vv;
        }
        // ----- PV channel-split: acc_o[mi][ni] += P[mi rows x 32k] @ V^T[wave ch x 32k]
#pragma unroll
        for (int k = 0; k < 4; ++k) {
            __syncthreads();         // P/alpha visible (k=0); V chunk arrived
            if (k < 3)        stageV((k + 1) & 1, kt, k + 1);
            else if (kt < 31) stageV(0, kt + 1, 0);
            if (k == 0 && kt < 31) stageK(0, kt + 1, 0);
            if (k == 0) {            // rescale O by per-row alpha (broadcast)
#pragma unroll
                for (int mi = 0; mi < 4; ++mi) {
                    float4 al = *(const float4*)(alpha_bc + mi * 16 + q * 4);
#pragma unroll
                    for (int ni = 0; ni < 4; ++ni) {
                        acc_o[mi * 4 + ni][0] *= al.x; acc_o[mi * 4 + ni][1] *= al.y;
                        acc_o[mi * 4 + ni][2] *= al.z; acc_o[mi * 4 + ni][3] *= al.w;
                    }
                }
            }
            short8 ap[4];
#pragma unroll
            for (int mi = 0; mi < 4; ++mi)
                ap[mi] = *(const short8*)(Pl + (mi * 16 + r) * 128 +
                                          (((k * 4 + q) ^ (r & 7)) * 8));
            const u16* vbase = Vs + (k & 1) * 16384;
#pragma unroll
            for (int ni = 0; ni < 4; ++ni) {
                short8 bf = *(const short8*)(vbase + (wch + ni * 16 + r) * 32 + swz);
#pragma unroll
                for (int mi = 0; mi < 4; ++mi)
                    acc_o[mi * 4 + ni] = __builtin_amdgcn_mfma_f32_16x16x32_bf16(
                        ap[mi], bf, acc_o[mi * 4 + ni], 0, 0, 0);
            }
        }
    }
    // ----- epilogue: exchange l halves, divide, store
    if (q == 0) mexl[w * 16 + r] = l_half;   // mexl[kh*64 + rw*16 + r]
    __syncthreads();
#pragma unroll
    for (int mi = 0; mi < 4; ++mi) {
        float4 la = *(const float4*)(mexl + mi * 16 + q * 4);        // kh=0 halves
        float4 lb = *(const float4*)(mexl + 64 + mi * 16 + q * 4);   // kh=1 halves
        float i0 = 1.f / (la.x + lb.x), i1 = 1.f / (la.y + lb.y);
        float i2 = 1.f / (la.z + lb.z), i3 = 1.f / (la.w + lb.w);
        int rowb = qt * 64 + mi * 16 + q * 4;
#pragma unroll
        for (int ni = 0; ni < 4; ++ni) {
            int col = wch + ni * 16 + r;
            aob[(size_t)(rowb + 0) * 512 + col] = f2b(acc_o[mi * 4 + ni][0] * i0);
            aob[(size_t)(rowb + 1) * 512 + col] = f2b(acc_o[mi * 4 + ni][1] * i1);
            aob[(size_t)(rowb + 2) * 512 + col] = f2b(acc_o[mi * 4 + ni][2] * i2);
            aob[(size_t)(rowb + 3) * 512 + col] = f2b(acc_o[mi * 4 + ni][3] * i3);
        }
    }
}

// ---------------------------------------------------------------------------
extern "C" void kernel_launch(void* const* d_in, const int* in_sizes, int n_in,
                              void* d_out, int out_size, void* d_ws, size_t ws_size,
                              hipStream_t stream) {
    const float* x     = (const float*)d_in[0];
    const float* gamma = (const float*)d_in[1];
    const float* beta  = (const float*)d_in[2];
    const float* Wq    = (const float*)d_in[3];
    const float* bq    = (const float*)d_in[4];
    const float* Wk    = (const float*)d_in[5];
    const float* bk    = (const float*)d_in[6];
    const float* Wv    = (const float*)d_in[7];
    const float* bv    = (const float*)d_in[8];
    const float* Wo    = (const float*)d_in[9];
    const float* bo    = (const float*)d_in[10];
    float* out = (float*)d_out;

    // B=4, N=4096, C=512, G=32 — ws layout
    char* ws = (char*)d_ws;
    float* stats  = (float*)(ws);                        // 128*2 f32
    float* bqkv   = (float*)(ws + 4096);                 // 1536 f32
    u16*   wqkv_t = (u16*)(ws + 16384);                  // [1536,512]
    u16*   wo_t   = wqkv_t + (size_t)1536 * 512;
    u16*   h      = wo_t + (size_t)512 * 512;            // [16384,512] (aliased as ao)
    u16*   qkv    = h   + (size_t)16384 * 512;           // [16384,1536]
    u16*   vt     = qkv + (size_t)16384 * 1536;          // [4][512][4096]
    u16*   ao     = h;                                   // h dead after QKV GEMM

    const long long sQKV = (long long)4096 * 1536;
    const long long sVT  = (long long)512 * 4096;

    dim3 tblk(32, 8, 1);
    transpose_f2b<<<dim3(16, 16, 1), tblk, 0, stream>>>(Wq, wqkv_t);
    transpose_f2b<<<dim3(16, 16, 1), tblk, 0, stream>>>(Wk, wqkv_t + 512 * 512);
    transpose_f2b<<<dim3(16, 16, 1), tblk, 0, stream>>>(Wv, wqkv_t + 1024 * 512);
    transpose_f2b<<<dim3(16, 16, 1), tblk, 0, stream>>>(Wo, wo_t);
    concat_bias_f<<<6, 256, 0, stream>>>(bq, bk, bv, bqkv);

    gn_stats_k<<<128, 256, 0, stream>>>(x, stats);
    gn_apply_k<<<8192, 256, 0, stream>>>(x, gamma, beta, stats, h);

    // QKV: [16384,512] @ [512,1536] -> qkv (+bias)
    gemm_bt<<<dim3(128, 12, 1), 256, 0, stream>>>(h, 512, wqkv_t, 512,
                                                  qkv, nullptr, 1536, bqkv, nullptr,
                                                  512, 1.0f);
    // v -> vt[b][c][n]
    transpose_b2b<<<dim3(128, 16, 4), tblk, 0, stream>>>(qkv + 1024, vt, 1536, 4096,
                                                         sQKV, sVT);
    // fused attention -> ao
    hipFuncSetAttribute((const void*)flash_k,
                        hipFuncAttributeMaxDynamicSharedMemorySize, FLASH_SMEM);
    flash_k<<<dim3(64, 4, 1), 512, FLASH_SMEM, stream>>>(qkv, vt, ao);

    // out = ao @ Wo + bo + x   (fp32 output + bias + residual)
    gemm_bt<<<dim3(128, 4, 1), 256, 0, stream>>>(ao, 512, wo_t, 512,
                                                 nullptr, out, 512, bo, x,
                                                 512, 1.0f);
}